// Round 4
// baseline (161.314 us; speedup 1.0000x reference)
//
#include <hip/hip_runtime.h>
#include <stdint.h>

// Trilinear grid_sample of 256^3 fp32 volume, x100. Round 4 (= Round 3 with
// compile fix: nontemporal builtins need native clang vector types, not
// HIP_vector_type). Bucket-routed pipeline: trilinear = wz0*bilerp(plane z0)
// + wz1*bilerp(plane z1); route the 2 contributions per point into
// (z, y-quarter) buckets; per-bucket block stages its 65-row quarter-plane
// COALESCED into LDS (bf16 x100) and serves all bilerps from LDS.

#define RES 256
#define NBUCK 1024          // 256 z-planes * 4 y-quarters
#define OVCAP 65536

typedef float v4f __attribute__((ext_vector_type(4)));
typedef float v2f __attribute__((ext_vector_type(2)));

// ---------- shared routing math ------------------------------------------
struct Route {
  float ix, iy;
  int bA, bB;
  float wA, wB;
};

__device__ __forceinline__ Route make_route(const float* __restrict__ x, int i) {
  float gx = x[3 * i + 0] * 2.0f;
  float gy = x[3 * i + 1] * 2.0f;
  float gz = x[3 * i + 2] * 2.0f;
  Route r;
  r.ix = ((gx + 1.0f) * 256.0f - 1.0f) * 0.5f;   // in [-0.5, 255.5]
  r.iy = ((gy + 1.0f) * 256.0f - 1.0f) * 0.5f;
  float iz = ((gz + 1.0f) * 256.0f - 1.0f) * 0.5f;
  float z0f = floorf(iz);
  float tz = iz - z0f;
  int z0 = (int)z0f;                              // in [-1, 255]
  int zA = max(z0, 0);
  int zB = min(z0 + 1, 255);
  r.wA = (z0 >= 0) ? (1.0f - tz) : 0.0f;
  r.wB = (z0 + 1 <= 255) ? tz : 0.0f;
  int y0 = (int)floorf(r.iy);                     // in [-1, 255]
  int q = min(max(y0, 0) >> 6, 3);                // quarter containing rows y0,y0+1
  r.bA = zA * 4 + q;
  r.bB = zB * 4 + q;
  return r;
}

// bf16 round-to-nearest-even (values are finite, never NaN)
__device__ __forceinline__ uint16_t bf16_rne(float f) {
  uint32_t u = __float_as_uint(f);
  u += 0x7FFFu + ((u >> 16) & 1u);
  return (uint16_t)(u >> 16);
}
__device__ __forceinline__ float b2f(uint16_t h) {
  return __uint_as_float(((uint32_t)h) << 16);
}

// ---------- kernel 1: fused LDS-hist + reservation + scatter ---------------
__global__ __launch_bounds__(1024) void scatter_kernel(
    const float* __restrict__ x,
    uint32_t* __restrict__ cur,      // [NBUCK] bucket fill counts (pre-zeroed)
    uint32_t* __restrict__ ovn,      // overflow count (pre-zeroed)
    uint32_t* __restrict__ ovbkt,    // [OVCAP]
    v4f* __restrict__ ovrec,         // [OVCAP]
    v4f* __restrict__ recs,          // [NBUCK * cap]
    int cap, int n)
{
  __shared__ uint32_t lh[NBUCK];
  __shared__ uint32_t gb[NBUCK];
  int t = threadIdx.x;
  lh[t] = 0;
  __syncthreads();

  int i = blockIdx.x * 1024 + t;
  bool act = (i < n);
  Route r;
  uint32_t lrA = 0, lrB = 0;
  if (act) {
    r = make_route(x, i);
    lrA = atomicAdd(&lh[r.bA], 1u);
    lrB = atomicAdd(&lh[r.bB], 1u);
  }
  __syncthreads();

  uint32_t c = lh[t];
  gb[t] = c ? atomicAdd(&cur[t], c) : 0u;   // one global atomic per (block,bucket)
  __syncthreads();

  if (act) {
    v4f ra = { r.ix, r.iy, r.wA, __uint_as_float(2u * (uint32_t)i) };
    v4f rb = { r.ix, r.iy, r.wB, __uint_as_float(2u * (uint32_t)i + 1u) };
    uint32_t pA = gb[r.bA] + lrA;
    if (pA < (uint32_t)cap) {
      __builtin_nontemporal_store(ra, &recs[(size_t)r.bA * cap + pA]);
    } else {
      uint32_t o = atomicAdd(ovn, 1u);
      if (o < OVCAP) { ovbkt[o] = (uint32_t)r.bA; ovrec[o] = ra; }
    }
    uint32_t pB = gb[r.bB] + lrB;
    if (pB < (uint32_t)cap) {
      __builtin_nontemporal_store(rb, &recs[(size_t)r.bB * cap + pB]);
    } else {
      uint32_t o = atomicAdd(ovn, 1u);
      if (o < OVCAP) { ovbkt[o] = (uint32_t)r.bB; ovrec[o] = rb; }
    }
  }
}

// ---------- kernel 2: per-bucket LDS bilerp ------------------------------
__device__ __forceinline__ void process_rec(
    v4f rec, const uint16_t* __restrict__ plane, int sq,
    float* __restrict__ partial)
{
  float ixf = rec.x, iyf = rec.y, w = rec.z;
  uint32_t dest = __float_as_uint(rec.w);
  float x0f = floorf(ixf); float tx = ixf - x0f; int x0 = (int)x0f;
  float y0f = floorf(iyf); float ty = iyf - y0f; int y0 = (int)y0f;
  float wx0 = (x0 >= 0)   ? (1.0f - tx) : 0.0f;
  float wx1 = (x0 <= 254) ? tx : 0.0f;
  float wy0 = (y0 >= 0)   ? (1.0f - ty) : 0.0f;
  float wy1 = (y0 <= 254) ? ty : 0.0f;
  int xc0 = max(x0, 0), xc1 = min(x0 + 1, 255);
  int ly0 = max(y0, 0) - sq;          // in [0,64] by quarter construction
  int ly1 = min(y0 + 1, 255) - sq;    // in [0,64]
  float v00 = b2f(plane[ly0 * 258 + xc0]);
  float v01 = b2f(plane[ly0 * 258 + xc1]);
  float v10 = b2f(plane[ly1 * 258 + xc0]);
  float v11 = b2f(plane[ly1 * 258 + xc1]);
  float bil = (v00 * wx0 + v01 * wx1) * wy0 + (v10 * wx0 + v11 * wx1) * wy1;
  partial[dest] = w * bil;
}

__global__ __launch_bounds__(256) void gather_kernel(
    const float* __restrict__ vol,
    const v4f* __restrict__ recs,
    const uint32_t* __restrict__ cur,
    const uint32_t* __restrict__ ovn,
    const uint32_t* __restrict__ ovbkt,
    const v4f* __restrict__ ovrec,
    float* __restrict__ partial, int cap)
{
  int b = blockIdx.x;
  int z = b >> 2, q = b & 3;
  int sq = (q == 3) ? 191 : (q << 6);   // quarter row starts: 0,64,128,191
  __shared__ uint16_t plane[65 * 258];  // 65 rows, +2 pad (33540 B)

  // coalesced staging: 65 rows x 256 floats, as float4
  const float* src = vol + ((size_t)(z * 256 + sq) * 256);
  for (int e = threadIdx.x; e < 65 * 64; e += 256) {
    int rr = e >> 6, c4 = (e & 63) << 2;
    v4f v = __builtin_nontemporal_load((const v4f*)(src + (size_t)rr * 256) + (e & 63));
    int o = rr * 258 + c4;
    plane[o + 0] = bf16_rne(100.0f * v.x);
    plane[o + 1] = bf16_rne(100.0f * v.y);
    plane[o + 2] = bf16_rne(100.0f * v.z);
    plane[o + 3] = bf16_rne(100.0f * v.w);
  }
  __syncthreads();

  uint32_t cnt = min(cur[b], (uint32_t)cap);
  const v4f* rb = recs + (size_t)b * cap;
  for (uint32_t j = threadIdx.x; j < cnt; j += 256) {
    v4f rec = __builtin_nontemporal_load(&rb[j]);
    process_rec(rec, plane, sq, partial);
  }

  // exact overflow handling (normally empty)
  uint32_t nov = min(*ovn, (uint32_t)OVCAP);
  for (uint32_t j = threadIdx.x; j < nov; j += 256) {
    if (ovbkt[j] == (uint32_t)b) process_rec(ovrec[j], plane, sq, partial);
  }
}

// ---------- kernel 3: combine the two z-contributions --------------------
__global__ __launch_bounds__(256) void combine_kernel(
    const float* __restrict__ partial, float* __restrict__ out, int n)
{
  int i = blockIdx.x * 256 + threadIdx.x;
  if (i < n) {
    v2f p = __builtin_nontemporal_load((const v2f*)partial + i);
    __builtin_nontemporal_store(p.x + p.y, &out[i]);
  }
}

// ---------- fallback: direct gather (R1 kernel) --------------------------
__global__ __launch_bounds__(256) void direct_kernel(
    const float* __restrict__ x, const float* __restrict__ vol,
    float* __restrict__ out, int n)
{
  int i = blockIdx.x * blockDim.x + threadIdx.x;
  if (i >= n) return;
  float gx = x[3 * i + 0] * 2.0f;
  float gy = x[3 * i + 1] * 2.0f;
  float gz = x[3 * i + 2] * 2.0f;
  float ix = ((gx + 1.0f) * 256.0f - 1.0f) * 0.5f;
  float iy = ((gy + 1.0f) * 256.0f - 1.0f) * 0.5f;
  float iz = ((gz + 1.0f) * 256.0f - 1.0f) * 0.5f;
  float x0f = floorf(ix), y0f = floorf(iy), z0f = floorf(iz);
  float tx = ix - x0f, ty = iy - y0f, tz = iz - z0f;
  int x0 = (int)x0f, y0 = (int)y0f, z0 = (int)z0f;
  float wx0 = (x0 >= 0 && x0 < 256) ? (1.0f - tx) : 0.0f;
  float wx1 = (x0 + 1 >= 0 && x0 + 1 < 256) ? tx : 0.0f;
  float wy0 = (y0 >= 0 && y0 < 256) ? (1.0f - ty) : 0.0f;
  float wy1 = (y0 + 1 >= 0 && y0 + 1 < 256) ? ty : 0.0f;
  float wz0 = (z0 >= 0 && z0 < 256) ? (1.0f - tz) : 0.0f;
  float wz1 = (z0 + 1 >= 0 && z0 + 1 < 256) ? tz : 0.0f;
  int xc0 = min(max(x0, 0), 255), xc1 = min(max(x0 + 1, 0), 255);
  int yc0 = min(max(y0, 0), 255), yc1 = min(max(y0 + 1, 0), 255);
  int zc0 = min(max(z0, 0), 255), zc1 = min(max(z0 + 1, 0), 255);
  int r00 = (zc0 * 256 + yc0) * 256;
  int r01 = (zc0 * 256 + yc1) * 256;
  int r10 = (zc1 * 256 + yc0) * 256;
  int r11 = (zc1 * 256 + yc1) * 256;
  float v000 = vol[r00 + xc0], v001 = vol[r00 + xc1];
  float v010 = vol[r01 + xc0], v011 = vol[r01 + xc1];
  float v100 = vol[r10 + xc0], v101 = vol[r10 + xc1];
  float v110 = vol[r11 + xc0], v111 = vol[r11 + xc1];
  float c00 = v000 * wx0 + v001 * wx1;
  float c01 = v010 * wx0 + v011 * wx1;
  float c10 = v100 * wx0 + v101 * wx1;
  float c11 = v110 * wx0 + v111 * wx1;
  float c0 = c00 * wy0 + c01 * wy1;
  float c1 = c10 * wy0 + c11 * wy1;
  out[i] = 100.0f * (c0 * wz0 + c1 * wz1);
}

extern "C" void kernel_launch(void* const* d_in, const int* in_sizes, int n_in,
                              void* d_out, int out_size, void* d_ws, size_t ws_size,
                              hipStream_t stream) {
  const float* x   = (const float*)d_in[0];   // [8, 65536, 3] fp32
  const float* vol = (const float*)d_in[1];   // [256,256,256] fp32
  float* out = (float*)d_out;                 // [8, 65536] fp32
  int n = out_size;                           // 524288

  // workspace layout
  const size_t cur_off   = 0;                      // 1024 u32
  const size_t ovbkt_off = 8192;                   // OVCAP u32 = 262144 B
  const size_t ovrec_off = 270336;                 // OVCAP v4f = 1048576 B
  const size_t recs_off  = 1318912;                // NBUCK * cap * 16
  int cap = (2 * n + NBUCK - 1) / NBUCK;           // mean per bucket
  cap = cap + cap / 4 + 64;                        // +25% headroom (overflow list exact anyway)
  size_t recs_bytes = (size_t)NBUCK * cap * 16;
  size_t partial_off = recs_off + recs_bytes;
  size_t need = partial_off + (size_t)2 * n * 4;

  if (ws_size >= need && n >= 1024) {
    char* ws = (char*)d_ws;
    uint32_t* cur   = (uint32_t*)(ws + cur_off);
    uint32_t* ovn   = (uint32_t*)(ws + 4096);
    uint32_t* ovbkt = (uint32_t*)(ws + ovbkt_off);
    v4f*      ovrec = (v4f*)(ws + ovrec_off);
    v4f*      recs  = (v4f*)(ws + recs_off);
    float*    partial = (float*)(ws + partial_off);

    (void)hipMemsetAsync(ws, 0, 8192, stream);  // cur + ovn
    scatter_kernel<<<(n + 1023) / 1024, 1024, 0, stream>>>(
        x, cur, ovn, ovbkt, ovrec, recs, cap, n);
    gather_kernel<<<NBUCK, 256, 0, stream>>>(
        vol, recs, cur, ovn, ovbkt, ovrec, partial, cap);
    combine_kernel<<<(n + 255) / 256, 256, 0, stream>>>(partial, out, n);
  } else {
    direct_kernel<<<(n + 255) / 256, 256, 0, stream>>>(x, vol, out, n);
  }
}